// Round 5
// baseline (413.419 us; speedup 1.0000x reference)
//
#include <hip/hip_runtime.h>
#include <stdint.h>

// RGCN round 5: all-e spmm accumulating in-place into hs (part buffer gone),
// XCD-local b placement, atomic-free deg, k_cast folded into gemm<F32IN>.
//
//   k_pack: adj (134 MB, read once) -> bitmask (4 MB) + per-(e,b) deg partials
//   k_inv:  inv = 1/sum_e degp
//   k_prep: all 8 weight mats -> k-packed bf16 64-col MFMA blocks
//   per layer:
//     k_gemm<K,F32IN>: grid(256,10): by<2 self cols -> hs (f32);
//                      by>=2 edge (fixed e) -> mmp bf16 k-packed, inv folded
//     k_spmm: grid 256 (oc,nt,b; b low bits -> same-XCD L2 reuse of mmp):
//             all 4 e accumulated in-block; hs += adjbits @ mmp (no partials)
//     k_bnstat: block per node n: BN stats over (b,o) of hs, norm+ReLU -> bf16
//   head: gemm w1 -> bnstat -> gemm w2 -> d_out (f32)

typedef float  f32x4  __attribute__((ext_vector_type(4)));
typedef __bf16 bf16x8 __attribute__((ext_vector_type(8)));
typedef __bf16 bf16x4 __attribute__((ext_vector_type(4)));
typedef unsigned short ushort8v __attribute__((ext_vector_type(8)));
typedef uint32_t uint4v __attribute__((ext_vector_type(4)));

#define MBATCH 32
#define ETYPES 4
#define NNODE  512
#define HIDD   128

#define GLB(p) (const __attribute__((address_space(1))) uint32_t*)(p)
#define LDSp(p) (__attribute__((address_space(3))) uint32_t*)(p)

// packed-weight pool offsets (elements)
#define WP_S0 0
#define WP_E0 8192
#define WP_S1 40960
#define WP_E1 57344
#define WP_S2 122880
#define WP_E2 139264
#define WP_W1 204800
#define WP_W2 221184

// ---------------- pack: adj -> bitmask + per-(e,b) deg partials ----------------
__global__ __launch_bounds__(256) void k_pack(const float* __restrict__ adj,
                                              uint32_t* __restrict__ bm,
                                              float* __restrict__ degp) {
  int t = threadIdx.x;
  int wave = t >> 6, lane = t & 63;
  int r = blockIdx.x * 4 + wave;          // 65536 rows (b,e,n)
  int b = r >> 11, e = (r >> 9) & 3, n = r & 511;
  const float* row = adj + (long)r * 512;
  uint32_t myw = 0;
#pragma unroll
  for (int i = 0; i < 8; ++i) {
    uint64_t bal = __ballot(row[i * 64 + lane] != 0.f);
    uint32_t lo = (uint32_t)bal, hi = (uint32_t)(bal >> 32);
    if ((lane >> 1) == i) myw = (lane & 1) ? hi : lo;
  }
  if (lane == (n >> 5)) myw &= ~(1u << (n & 31));   // zero diagonal
  int pc = (lane < 16) ? __popc(myw) : 0;
  pc += __shfl_down(pc, 8);
  pc += __shfl_down(pc, 4);
  pc += __shfl_down(pc, 2);
  pc += __shfl_down(pc, 1);
  if (lane < 16) bm[(long)r * 16 + lane] = myw;
  if (lane == 0) degp[e * 16384 + b * 512 + n] = (float)pc;   // plain store
}

__global__ __launch_bounds__(256) void k_inv(const float* __restrict__ degp,
                                             float* __restrict__ inv) {
  int i = blockIdx.x * 256 + threadIdx.x;   // 16384
  float d = degp[i] + degp[16384 + i] + degp[32768 + i] + degp[49152 + i];
  inv[i] = d > 0.f ? 1.f / d : 0.f;
}

// ---------------- prep: pack weights to bf16 k-packed 64-col blocks ----------------
__global__ __launch_bounds__(256) void k_prep(const float* ws0, const float* we0,
                                              const float* ws1, const float* we1,
                                              const float* ws2, const float* we2,
                                              const float* w1,  const float* w2,
                                              __bf16* __restrict__ dst) {
  int wid = blockIdx.y;
  const float* W; int K, nblk, edge, off;
  switch (wid) {
    case 0:  W = ws0; K = 64;  nblk = 2; edge = 0; off = WP_S0; break;
    case 1:  W = we0; K = 64;  nblk = 8; edge = 1; off = WP_E0; break;
    case 2:  W = ws1; K = 128; nblk = 2; edge = 0; off = WP_S1; break;
    case 3:  W = we1; K = 128; nblk = 8; edge = 1; off = WP_E1; break;
    case 4:  W = ws2; K = 128; nblk = 2; edge = 0; off = WP_S2; break;
    case 5:  W = we2; K = 128; nblk = 8; edge = 1; off = WP_E2; break;
    case 6:  W = w1;  K = 128; nblk = 2; edge = 0; off = WP_W1; break;
    default: W = w2;  K = 128; nblk = 2; edge = 0; off = WP_W2; break;
  }
  int idx = blockIdx.x * 256 + threadIdx.x;
  if (idx >= K * nblk * 64) return;
  int c = idx & 63;
  int k = (idx >> 6) % K;
  int blk = (idx >> 6) / K;
  int WS = edge ? 512 : 128;
  int col = edge ? (((blk & 1) * 64 + c) * 4 + (blk >> 1)) : (blk * 64 + c);
  dst[off + (long)blk * K * 64 + (k >> 3) * 512 + c * 8 + (k & 7)] = (__bf16)W[k * WS + col];
}

// ---------------- fused self+edge bf16 MFMA linear ----------------
// grid (256, NY). by<2: self cols c0=by*64 -> outF (f32, +bias).
// by>=2: edge block blk=by-2 (fixed e, 64 o's) -> mmp bf16 k-packed, *inv.
// F32IN: h is fp32 (layer-0 x), converted during LDS staging.
template <int K, bool F32IN>
__global__ __launch_bounds__(256) void k_gemm(const void* __restrict__ hv,
                                              const __bf16* __restrict__ wp_self,
                                              const float* __restrict__ bias_self,
                                              const __bf16* __restrict__ wp_edge,
                                              const float* __restrict__ bias_edge,
                                              const float* __restrict__ invp,
                                              float* __restrict__ outF,
                                              __bf16* __restrict__ mmp) {
  __shared__ __bf16 Hl[64][K + 8];
  __shared__ __align__(16) __bf16 Wl[K * 64];   // k-packed [K/8][64][8]
  int t = threadIdx.x;
  int g0 = blockIdx.x * 64;
  int by = blockIdx.y;
  bool edge = by >= 2;
  int wave = t >> 6, lane = t & 63;
  // stage W: contiguous K*128-byte copy via global_load_lds
  {
    const __bf16* wblk = edge ? (wp_edge + (long)(by - 2) * K * 64)
                              : (wp_self + (long)by * K * 64);
    const char* g = (const char*)wblk;
#pragma unroll
    for (int i = 0; i < K / 32; ++i) {
      __builtin_amdgcn_global_load_lds(GLB(g + i * 4096 + wave * 1024 + lane * 16),
                                       LDSp((char*)Wl + i * 4096 + wave * 1024),
                                       16, 0, 0);
    }
  }
  // stage H (coalesced, padded rows)
  for (int idx = t; idx < 64 * (K / 8); idx += 256) {
    int r = idx / (K / 8), ch = idx % (K / 8);
    if (F32IN) {
      const float* xf = (const float*)hv;
      f32x4 a = *(const f32x4*)(xf + (long)(g0 + r) * K + ch * 8);
      f32x4 bq = *(const f32x4*)(xf + (long)(g0 + r) * K + ch * 8 + 4);
      bf16x8 o;
#pragma unroll
      for (int j = 0; j < 4; ++j) { o[j] = (__bf16)a[j]; o[4 + j] = (__bf16)bq[j]; }
      *(bf16x8*)&Hl[r][ch * 8] = o;
    } else {
      const __bf16* hb = (const __bf16*)hv;
      *(bf16x8*)&Hl[r][ch * 8] = *(const bf16x8*)(hb + (long)(g0 + r) * K + ch * 8);
    }
  }
  __syncthreads();
  int l15 = lane & 15, q = lane >> 4;
  f32x4 acc[4] = {};
#pragma unroll
  for (int kk = 0; kk < K / 32; ++kk) {
    bf16x8 af = *(const bf16x8*)&Hl[wave * 16 + l15][kk * 32 + q * 8];
#pragma unroll
    for (int c = 0; c < 4; ++c) {
      bf16x8 bfr = *(const bf16x8*)&Wl[((kk * 4 + q) * 64 + c * 16 + l15) * 8];
      acc[c] = __builtin_amdgcn_mfma_f32_16x16x32_bf16(af, bfr, acc[c], 0, 0, 0);
    }
  }
  // D: row = q*4+i (within wave's 16-row tile), col = c*16+l15
  if (!edge) {
    int c0 = by * 64;
#pragma unroll
    for (int c = 0; c < 4; ++c) {
      float bc = bias_self[c0 + c * 16 + l15];
#pragma unroll
      for (int i = 0; i < 4; ++i) {
        int g = g0 + wave * 16 + q * 4 + i;
        outF[(long)g * HIDD + c0 + c * 16 + l15] = acc[c][i] + bc;
      }
    }
  } else {
    int blk = by - 2;
    int e = blk >> 1, o0 = (blk & 1) * 64;
    float iv[4];
#pragma unroll
    for (int i = 0; i < 4; ++i) iv[i] = invp[g0 + wave * 16 + q * 4 + i];
    int b4e  = (g0 >> 9) * 4 + e;
    int octg = ((g0 & 511) >> 3) + wave * 2 + (q >> 1);
    int j0   = (q & 1) * 4;
#pragma unroll
    for (int c = 0; c < 4; ++c) {
      int o = o0 + c * 16 + l15;
      float bc = bias_edge[o * 4 + e];
      bf16x4 v4;
#pragma unroll
      for (int i = 0; i < 4; ++i) v4[i] = (__bf16)((acc[c][i] + bc) * iv[i]);
      *(bf16x4*)(mmp + ((long)(b4e * 64 + octg) * HIDD + o) * 8 + j0) = v4;
    }
  }
}

// ---------------- spmm: hs += sum_e adjbits(bf16 0/1) @ mmp ----------------
// grid 256: bid = ((oc*4)+nt)*32 + b  (b in low bits -> all blocks of a batch
// on one XCD -> mmp slice L2-resident). Block 128 rows x 64 cols, all 4 e.
__global__ __launch_bounds__(256) void k_spmm(const uint32_t* __restrict__ bm,
                                              const __bf16* __restrict__ mmp,
                                              float* __restrict__ hs) {
  __shared__ __align__(16) __bf16 Bl[4096];   // [oct(8)][o_local(64)][j(8)] = 8 KB
  int t = threadIdx.x;
  int bid = blockIdx.x;
  int b = bid & 31, nt = (bid >> 5) & 3, oc = bid >> 7;
  int n0 = nt * 128, o0 = oc * 64;
  int wave = t >> 6, lane = t & 63, l15 = lane & 15, q = lane >> 4;

  f32x4 acc0[4] = {}, acc1[4] = {};
  for (int e = 0; e < 4; ++e) {
    const uint32_t* bmr = bm + ((long)((b * 4 + e) * 512 + n0 + wave * 32 + l15)) * 16;
    uint32_t rm0[16], rm1[16];
#pragma unroll
    for (int i = 0; i < 4; ++i) {
      uint4v v0 = *(const uint4v*)(bmr + i * 4);
      uint4v v1 = *(const uint4v*)(bmr + 256 + i * 4);   // +16 rows * 16 words
      rm0[i * 4 + 0] = v0.x; rm0[i * 4 + 1] = v0.y; rm0[i * 4 + 2] = v0.z; rm0[i * 4 + 3] = v0.w;
      rm1[i * 4 + 0] = v1.x; rm1[i * 4 + 1] = v1.y; rm1[i * 4 + 2] = v1.z; rm1[i * 4 + 3] = v1.w;
    }
    const __bf16* Bbase = mmp + (long)(b * 4 + e) * 65536;
#pragma unroll 1
    for (int mc = 0; mc < 8; ++mc) {
      __syncthreads();   // Bl free from previous iter
      // stage this (e,mc) chunk's o-half: 8 octs x 64 o x 8 j = 8 KB
#pragma unroll
      for (int i = 0; i < 2; ++i) {
        int oct = wave * 2 + i;
        const char* g = (const char*)mmp +
            ((long)(b * 4 + e) * 65536 + mc * 8192 + oct * 1024 + o0 * 8) * 2;
        __builtin_amdgcn_global_load_lds(GLB(g + lane * 16),
                                         LDSp((char*)Bl + oct * 1024),
                                         16, 0, 0);
      }
      __syncthreads();   // loads drained
#pragma unroll
      for (int kk = 0; kk < 2; ++kk) {
        uint32_t bits0 = (rm0[mc * 2 + kk] >> (q * 8)) & 0xffu;
        uint32_t bits1 = (rm1[mc * 2 + kk] >> (q * 8)) & 0xffu;
        ushort8v a0, a1;
#pragma unroll
        for (int j = 0; j < 8; ++j) {
          a0[j] = (bits0 >> j & 1u) ? (unsigned short)0x3F80 : (unsigned short)0;
          a1[j] = (bits1 >> j & 1u) ? (unsigned short)0x3F80 : (unsigned short)0;
        }
        union { ushort8v u; bf16x8 v; } c0, c1; c0.u = a0; c1.u = a1;
#pragma unroll
        for (int c = 0; c < 4; ++c) {
          bf16x8 bfr = *(const bf16x8*)&Bl[((kk * 4 + q) * 64 + c * 16 + l15) * 8];
          acc0[c] = __builtin_amdgcn_mfma_f32_16x16x32_bf16(c0.v, bfr, acc0[c], 0, 0, 0);
          acc1[c] = __builtin_amdgcn_mfma_f32_16x16x32_bf16(c1.v, bfr, acc1[c], 0, 0, 0);
        }
      }
    }
    __syncthreads();   // Bl consumed before next e reuses it
  }
#pragma unroll
  for (int c = 0; c < 4; ++c) {
#pragma unroll
    for (int i = 0; i < 4; ++i) {
      int n = n0 + wave * 32 + q * 4 + i;
      int o = o0 + c * 16 + l15;
      long idx = ((long)b * NNODE + n) * HIDD + o;
      hs[idx] += acc0[c][i];                    // sole writer of (b,n,o)
      hs[idx + 16 * HIDD] += acc1[c][i];
    }
  }
}

// ---------------- fused BN: stats over (b,o) of hs, norm+relu -> bf16 ----------------
__global__ __launch_bounds__(256) void k_bnstat(const float* __restrict__ hs,
                                                const float* __restrict__ gg,
                                                const float* __restrict__ bb,
                                                __bf16* __restrict__ hb) {
  int n = blockIdx.x, t = threadIdx.x;
  int o4 = t & 31, bq = t >> 5;
  __shared__ float sm[4096];
  __shared__ float rs[256], rq[256];
  __shared__ float bc[2];
  float s = 0.f, sq = 0.f;
#pragma unroll
  for (int i = 0; i < 4; ++i) {
    int b = bq + i * 8;
    f32x4 v = *(const f32x4*)(hs + ((long)b * NNODE + n) * HIDD + o4 * 4);
    *(f32x4*)&sm[b * 128 + o4 * 4] = v;
#pragma unroll
    for (int j = 0; j < 4; ++j) { s += v[j]; sq += v[j] * v[j]; }
  }
  rs[t] = s; rq[t] = sq;
  __syncthreads();
  for (int off = 128; off > 0; off >>= 1) {
    if (t < off) { rs[t] += rs[t + off]; rq[t] += rq[t + off]; }
    __syncthreads();
  }
  if (t == 0) {
    float mean = rs[0] * (1.f / 4096.f);
    float var = rq[0] * (1.f / 4096.f) - mean * mean;
    float rstd = rsqrtf(var + 1e-5f);
    float sc = gg[n] * rstd;
    bc[0] = sc;
    bc[1] = bb[n] - mean * sc;
  }
  __syncthreads();
  float sc = bc[0], sh = bc[1];
#pragma unroll
  for (int i = 0; i < 4; ++i) {
    int b = bq + i * 8;
    f32x4 v = *(const f32x4*)&sm[b * 128 + o4 * 4];
    bf16x4 o;
#pragma unroll
    for (int j = 0; j < 4; ++j) {
      float x = v[j] * sc + sh;
      o[j] = (__bf16)(x > 0.f ? x : 0.f);
    }
    *(bf16x4*)(hb + ((long)b * NNODE + n) * HIDD + o4 * 4) = o;
  }
}

extern "C" void kernel_launch(void* const* d_in, const int* in_sizes, int n_in,
                              void* d_out, int out_size, void* d_ws, size_t ws_size,
                              hipStream_t stream) {
  (void)in_sizes; (void)n_in; (void)out_size; (void)ws_size;
  const float* x   = (const float*)d_in[0];
  const float* adj = (const float*)d_in[1];
  const float* wself[3] = {(const float*)d_in[2],  (const float*)d_in[8],  (const float*)d_in[14]};
  const float* bself[3] = {(const float*)d_in[3],  (const float*)d_in[9],  (const float*)d_in[15]};
  const float* wedge[3] = {(const float*)d_in[4],  (const float*)d_in[10], (const float*)d_in[16]};
  const float* bedge[3] = {(const float*)d_in[5],  (const float*)d_in[11], (const float*)d_in[17]};
  const float* bng[3]   = {(const float*)d_in[6],  (const float*)d_in[12], (const float*)d_in[18]};
  const float* bnb[3]   = {(const float*)d_in[7],  (const float*)d_in[13], (const float*)d_in[19]};
  const float* w1   = (const float*)d_in[20];
  const float* b1   = (const float*)d_in[21];
  const float* bnfg = (const float*)d_in[22];
  const float* bnfb = (const float*)d_in[23];
  const float* w2   = (const float*)d_in[24];
  const float* b2   = (const float*)d_in[25];

  char* ws = (char*)d_ws;
  __bf16*   mmp  = (__bf16*)ws;                  // 16,777,216
  float*    hs   = (float*)(ws + 16777216);      //  8,388,608
  __bf16*   hb0  = (__bf16*)(ws + 25165824);     //  4,194,304
  __bf16*   hb1  = (__bf16*)(ws + 29360128);     //  4,194,304
  uint32_t* bm   = (uint32_t*)(ws + 33554432);   //  4,194,304
  float*    degp = (float*)(ws + 37748736);      //    262,144
  float*    inv  = (float*)(ws + 38010880);      //     65,536
  __bf16*   wp   = (__bf16*)(ws + 38076416);     //    475,136  -> ~38.6 MB total

  k_pack<<<16384, 256, 0, stream>>>(adj, bm, degp);
  k_inv<<<64, 256, 0, stream>>>(degp, inv);
  k_prep<<<dim3(256, 8), 256, 0, stream>>>(wself[0], wedge[0], wself[1], wedge[1],
                                           wself[2], wedge[2], w1, w2, wp);

  // layer 0 (K=64, fp32 input x converted in-staging)
  k_gemm<64, true><<<dim3(256, 10), 256, 0, stream>>>(x, wp + WP_S0, bself[0], wp + WP_E0,
                                                      bedge[0], inv, hs, mmp);
  k_spmm<<<256, 256, 0, stream>>>(bm, mmp, hs);
  k_bnstat<<<512, 256, 0, stream>>>(hs, bng[0], bnb[0], hb0);

  // layer 1 (K=128)
  k_gemm<128, false><<<dim3(256, 10), 256, 0, stream>>>(hb0, wp + WP_S1, bself[1], wp + WP_E1,
                                                        bedge[1], inv, hs, mmp);
  k_spmm<<<256, 256, 0, stream>>>(bm, mmp, hs);
  k_bnstat<<<512, 256, 0, stream>>>(hs, bng[1], bnb[1], hb1);

  // layer 2 (K=128)
  k_gemm<128, false><<<dim3(256, 10), 256, 0, stream>>>(hb1, wp + WP_S2, bself[2], wp + WP_E2,
                                                        bedge[2], inv, hs, mmp);
  k_spmm<<<256, 256, 0, stream>>>(bm, mmp, hs);
  k_bnstat<<<512, 256, 0, stream>>>(hs, bng[2], bnb[2], hb0);

  // head
  k_gemm<128, false><<<dim3(256, 2), 256, 0, stream>>>(hb0, wp + WP_W1, b1, nullptr,
                                                       nullptr, nullptr, hs, nullptr);
  k_bnstat<<<512, 256, 0, stream>>>(hs, bnfg, bnfb, hb1);
  k_gemm<128, false><<<dim3(256, 2), 256, 0, stream>>>(hb1, wp + WP_W2, b2, nullptr,
                                                       nullptr, nullptr, (float*)d_out, nullptr);
}

// Round 7
// 371.175 us; speedup vs baseline: 1.1138x; 1.1138x over previous
//
#include <hip/hip_runtime.h>
#include <stdint.h>

// RGCN round 7: r6 failed (absmax 14, root cause bracketed to dbuf-spmm /
// shuffle-bnstat / prep-merge). This round composes ONLY HW-proven pieces:
//   - spmm inner loop: r5 verbatim (2-barrier single-buffer, o-half staging)
//   - spmm epilogue:   r4 verbatim (part[e] plain stores)
//   - spmm grid:       1024 blocks (fixed e; tile = nt*2+oc) -> 4 blocks/CU
//   - bnstat:          r4 verbatim (tree reduce + part summing)
//   - k_pack/k_inv/k_prep/k_gemm: r5 verbatim
// Structure:
//   k_pack -> bitmask + deg partials; k_inv; k_prep (weights -> k-packed bf16)
//   per layer: k_gemm (self->hs f32, edge->mmp bf16 k-packed w/ inv folded)
//              k_spmm (part[e] = adjbits @ mmp, MFMA, bf16 {0,1} A from bits)
//              k_bnstat<true> (v = hs + sum_e part; BN over (b,o); relu; bf16)
//   head: gemm w1 -> bnstat<false> -> gemm w2 -> d_out (f32)

typedef float  f32x4  __attribute__((ext_vector_type(4)));
typedef __bf16 bf16x8 __attribute__((ext_vector_type(8)));
typedef __bf16 bf16x4 __attribute__((ext_vector_type(4)));
typedef unsigned short ushort8v __attribute__((ext_vector_type(8)));
typedef uint32_t uint4v __attribute__((ext_vector_type(4)));

#define MBATCH 32
#define ETYPES 4
#define NNODE  512
#define HIDD   128

#define GLB(p) (const __attribute__((address_space(1))) uint32_t*)(p)
#define LDSp(p) (__attribute__((address_space(3))) uint32_t*)(p)

// packed-weight pool offsets (elements)
#define WP_S0 0
#define WP_E0 8192
#define WP_S1 40960
#define WP_E1 57344
#define WP_S2 122880
#define WP_E2 139264
#define WP_W1 204800
#define WP_W2 221184

// ---------------- pack: adj -> bitmask + per-(e,b) deg partials ----------------
__global__ __launch_bounds__(256) void k_pack(const float* __restrict__ adj,
                                              uint32_t* __restrict__ bm,
                                              float* __restrict__ degp) {
  int t = threadIdx.x;
  int wave = t >> 6, lane = t & 63;
  int r = blockIdx.x * 4 + wave;          // 65536 rows (b,e,n)
  int b = r >> 11, e = (r >> 9) & 3, n = r & 511;
  const float* row = adj + (long)r * 512;
  uint32_t myw = 0;
#pragma unroll
  for (int i = 0; i < 8; ++i) {
    uint64_t bal = __ballot(row[i * 64 + lane] != 0.f);
    uint32_t lo = (uint32_t)bal, hi = (uint32_t)(bal >> 32);
    if ((lane >> 1) == i) myw = (lane & 1) ? hi : lo;
  }
  if (lane == (n >> 5)) myw &= ~(1u << (n & 31));   // zero diagonal
  int pc = (lane < 16) ? __popc(myw) : 0;
  pc += __shfl_down(pc, 8);
  pc += __shfl_down(pc, 4);
  pc += __shfl_down(pc, 2);
  pc += __shfl_down(pc, 1);
  if (lane < 16) bm[(long)r * 16 + lane] = myw;
  if (lane == 0) degp[e * 16384 + b * 512 + n] = (float)pc;   // plain store
}

__global__ __launch_bounds__(256) void k_inv(const float* __restrict__ degp,
                                             float* __restrict__ inv) {
  int i = blockIdx.x * 256 + threadIdx.x;   // 16384
  float d = degp[i] + degp[16384 + i] + degp[32768 + i] + degp[49152 + i];
  inv[i] = d > 0.f ? 1.f / d : 0.f;
}

// ---------------- prep: pack weights to bf16 k-packed 64-col blocks ----------------
__global__ __launch_bounds__(256) void k_prep(const float* ws0, const float* we0,
                                              const float* ws1, const float* we1,
                                              const float* ws2, const float* we2,
                                              const float* w1,  const float* w2,
                                              __bf16* __restrict__ dst) {
  int wid = blockIdx.y;
  const float* W; int K, nblk, edge, off;
  switch (wid) {
    case 0:  W = ws0; K = 64;  nblk = 2; edge = 0; off = WP_S0; break;
    case 1:  W = we0; K = 64;  nblk = 8; edge = 1; off = WP_E0; break;
    case 2:  W = ws1; K = 128; nblk = 2; edge = 0; off = WP_S1; break;
    case 3:  W = we1; K = 128; nblk = 8; edge = 1; off = WP_E1; break;
    case 4:  W = ws2; K = 128; nblk = 2; edge = 0; off = WP_S2; break;
    case 5:  W = we2; K = 128; nblk = 8; edge = 1; off = WP_E2; break;
    case 6:  W = w1;  K = 128; nblk = 2; edge = 0; off = WP_W1; break;
    default: W = w2;  K = 128; nblk = 2; edge = 0; off = WP_W2; break;
  }
  int idx = blockIdx.x * 256 + threadIdx.x;
  if (idx >= K * nblk * 64) return;
  int c = idx & 63;
  int k = (idx >> 6) % K;
  int blk = (idx >> 6) / K;
  int WS = edge ? 512 : 128;
  int col = edge ? (((blk & 1) * 64 + c) * 4 + (blk >> 1)) : (blk * 64 + c);
  dst[off + (long)blk * K * 64 + (k >> 3) * 512 + c * 8 + (k & 7)] = (__bf16)W[k * WS + col];
}

// ---------------- fused self+edge bf16 MFMA linear ----------------
// grid (256, NY). by<2: self cols c0=by*64 -> outF (f32, +bias).
// by>=2: edge block blk=by-2 (fixed e, 64 o's) -> mmp bf16 k-packed, *inv.
// F32IN: h is fp32 (layer-0 x), converted during LDS staging.
template <int K, bool F32IN>
__global__ __launch_bounds__(256) void k_gemm(const void* __restrict__ hv,
                                              const __bf16* __restrict__ wp_self,
                                              const float* __restrict__ bias_self,
                                              const __bf16* __restrict__ wp_edge,
                                              const float* __restrict__ bias_edge,
                                              const float* __restrict__ invp,
                                              float* __restrict__ outF,
                                              __bf16* __restrict__ mmp) {
  __shared__ __bf16 Hl[64][K + 8];
  __shared__ __align__(16) __bf16 Wl[K * 64];   // k-packed [K/8][64][8]
  int t = threadIdx.x;
  int g0 = blockIdx.x * 64;
  int by = blockIdx.y;
  bool edge = by >= 2;
  int wave = t >> 6, lane = t & 63;
  // stage W: contiguous K*128-byte copy via global_load_lds
  {
    const __bf16* wblk = edge ? (wp_edge + (long)(by - 2) * K * 64)
                              : (wp_self + (long)by * K * 64);
    const char* g = (const char*)wblk;
#pragma unroll
    for (int i = 0; i < K / 32; ++i) {
      __builtin_amdgcn_global_load_lds(GLB(g + i * 4096 + wave * 1024 + lane * 16),
                                       LDSp((char*)Wl + i * 4096 + wave * 1024),
                                       16, 0, 0);
    }
  }
  // stage H (coalesced, padded rows)
  for (int idx = t; idx < 64 * (K / 8); idx += 256) {
    int r = idx / (K / 8), ch = idx % (K / 8);
    if (F32IN) {
      const float* xf = (const float*)hv;
      f32x4 a = *(const f32x4*)(xf + (long)(g0 + r) * K + ch * 8);
      f32x4 bq = *(const f32x4*)(xf + (long)(g0 + r) * K + ch * 8 + 4);
      bf16x8 o;
#pragma unroll
      for (int j = 0; j < 4; ++j) { o[j] = (__bf16)a[j]; o[4 + j] = (__bf16)bq[j]; }
      *(bf16x8*)&Hl[r][ch * 8] = o;
    } else {
      const __bf16* hb = (const __bf16*)hv;
      *(bf16x8*)&Hl[r][ch * 8] = *(const bf16x8*)(hb + (long)(g0 + r) * K + ch * 8);
    }
  }
  __syncthreads();
  int l15 = lane & 15, q = lane >> 4;
  f32x4 acc[4] = {};
#pragma unroll
  for (int kk = 0; kk < K / 32; ++kk) {
    bf16x8 af = *(const bf16x8*)&Hl[wave * 16 + l15][kk * 32 + q * 8];
#pragma unroll
    for (int c = 0; c < 4; ++c) {
      bf16x8 bfr = *(const bf16x8*)&Wl[((kk * 4 + q) * 64 + c * 16 + l15) * 8];
      acc[c] = __builtin_amdgcn_mfma_f32_16x16x32_bf16(af, bfr, acc[c], 0, 0, 0);
    }
  }
  // D: row = q*4+i (within wave's 16-row tile), col = c*16+l15
  if (!edge) {
    int c0 = by * 64;
#pragma unroll
    for (int c = 0; c < 4; ++c) {
      float bc = bias_self[c0 + c * 16 + l15];
#pragma unroll
      for (int i = 0; i < 4; ++i) {
        int g = g0 + wave * 16 + q * 4 + i;
        outF[(long)g * HIDD + c0 + c * 16 + l15] = acc[c][i] + bc;
      }
    }
  } else {
    int blk = by - 2;
    int e = blk >> 1, o0 = (blk & 1) * 64;
    float iv[4];
#pragma unroll
    for (int i = 0; i < 4; ++i) iv[i] = invp[g0 + wave * 16 + q * 4 + i];
    int b4e  = (g0 >> 9) * 4 + e;
    int octg = ((g0 & 511) >> 3) + wave * 2 + (q >> 1);
    int j0   = (q & 1) * 4;
#pragma unroll
    for (int c = 0; c < 4; ++c) {
      int o = o0 + c * 16 + l15;
      float bc = bias_edge[o * 4 + e];
      bf16x4 v4;
#pragma unroll
      for (int i = 0; i < 4; ++i) v4[i] = (__bf16)((acc[c][i] + bc) * iv[i]);
      *(bf16x4*)(mmp + ((long)(b4e * 64 + octg) * HIDD + o) * 8 + j0) = v4;
    }
  }
}

// ---------------- spmm: part[e] = adjbits(bf16 0/1) @ mmp ----------------
// grid 1024: bid = tile*128 + e*32 + b, tile = nt*2 + oc. Fixed e per block.
// Block = 128 rows x 64 cols; wave = 2 x 16-row tiles sharing each B-frag
// ds_read_b128. r5-proven 2-barrier loop (stage -> barrier -> consume).
__global__ __launch_bounds__(256) void k_spmm(const uint32_t* __restrict__ bm,
                                              const __bf16* __restrict__ mmp,
                                              float* __restrict__ part) {
  __shared__ __align__(16) __bf16 Bl[4096];   // [oct(8)][o_local(64)][j(8)] = 8 KB
  int t = threadIdx.x;
  int bid = blockIdx.x;
  int tile = bid >> 7;          // 0..7 = nt*2 + oc
  int eb   = bid & 127;         // e*32 + b
  int e = eb >> 5, b = eb & 31;
  int nt = tile >> 1, oc = tile & 1;
  int n0 = nt * 128, o0 = oc * 64;
  int wave = t >> 6, lane = t & 63, l15 = lane & 15, q = lane >> 4;

  // bitmask rows: tile0 = n0 + wave*32 + l15, tile1 = +16 (q-replicated)
  const uint32_t* bmr = bm + ((long)((b * 4 + e) * 512 + n0 + wave * 32 + l15)) * 16;
  uint32_t rm0[16], rm1[16];
#pragma unroll
  for (int i = 0; i < 4; ++i) {
    uint4v v0 = *(const uint4v*)(bmr + i * 4);
    uint4v v1 = *(const uint4v*)(bmr + 256 + i * 4);   // +16 rows * 16 words
    rm0[i * 4 + 0] = v0.x; rm0[i * 4 + 1] = v0.y; rm0[i * 4 + 2] = v0.z; rm0[i * 4 + 3] = v0.w;
    rm1[i * 4 + 0] = v1.x; rm1[i * 4 + 1] = v1.y; rm1[i * 4 + 2] = v1.z; rm1[i * 4 + 3] = v1.w;
  }

  f32x4 acc0[4] = {}, acc1[4] = {};
#pragma unroll 1
  for (int mc = 0; mc < 8; ++mc) {
    __syncthreads();   // Bl free from previous iter
    // stage this mc chunk's o-half: 8 octs x 64 o x 8 j = 8 KB
#pragma unroll
    for (int i = 0; i < 2; ++i) {
      int oct = wave * 2 + i;
      const char* g = (const char*)mmp +
          ((long)(b * 4 + e) * 65536 + mc * 8192 + oct * 1024 + o0 * 8) * 2;
      __builtin_amdgcn_global_load_lds(GLB(g + lane * 16),
                                       LDSp((char*)Bl + oct * 1024),
                                       16, 0, 0);
    }
    __syncthreads();   // loads drained
#pragma unroll
    for (int kk = 0; kk < 2; ++kk) {
      uint32_t bits0 = (rm0[mc * 2 + kk] >> (q * 8)) & 0xffu;
      uint32_t bits1 = (rm1[mc * 2 + kk] >> (q * 8)) & 0xffu;
      ushort8v a0, a1;
#pragma unroll
      for (int j = 0; j < 8; ++j) {
        a0[j] = (bits0 >> j & 1u) ? (unsigned short)0x3F80 : (unsigned short)0;
        a1[j] = (bits1 >> j & 1u) ? (unsigned short)0x3F80 : (unsigned short)0;
      }
      union { ushort8v u; bf16x8 v; } c0, c1; c0.u = a0; c1.u = a1;
#pragma unroll
      for (int c = 0; c < 4; ++c) {
        bf16x8 bfr = *(const bf16x8*)&Bl[((kk * 4 + q) * 64 + c * 16 + l15) * 8];
        acc0[c] = __builtin_amdgcn_mfma_f32_16x16x32_bf16(c0.v, bfr, acc0[c], 0, 0, 0);
        acc1[c] = __builtin_amdgcn_mfma_f32_16x16x32_bf16(c1.v, bfr, acc1[c], 0, 0, 0);
      }
    }
  }
  float* dst = part + (long)(e * 32 + b) * NNODE * HIDD;
#pragma unroll
  for (int c = 0; c < 4; ++c) {
#pragma unroll
    for (int i = 0; i < 4; ++i) {
      int n = n0 + wave * 32 + q * 4 + i;
      int o = o0 + c * 16 + l15;
      dst[(long)n * HIDD + o] = acc0[c][i];
      dst[(long)(n + 16) * HIDD + o] = acc1[c][i];
    }
  }
}

// ---------------- fused BN: v = hs (+ sum_e part), stats over (b,o), norm+relu -> bf16 ----------------
template <bool HASP>
__global__ __launch_bounds__(256) void k_bnstat(const float* __restrict__ hs,
                                                const float* __restrict__ part,
                                                const float* __restrict__ gg,
                                                const float* __restrict__ bb,
                                                __bf16* __restrict__ hb) {
  int n = blockIdx.x, t = threadIdx.x;
  int o4 = t & 31, bq = t >> 5;
  __shared__ float sm[4096];
  __shared__ float rs[256], rq[256];
  __shared__ float bc[2];
  float s = 0.f, sq = 0.f;
#pragma unroll
  for (int i = 0; i < 4; ++i) {
    int b = bq + i * 8;
    long base = ((long)b * NNODE + n) * HIDD + o4 * 4;
    f32x4 v = *(const f32x4*)(hs + base);
    if (HASP) {
#pragma unroll
      for (int e = 0; e < 4; ++e)
        v += *(const f32x4*)(part + ((long)(e * 32 + b) * NNODE + n) * HIDD + o4 * 4);
    }
    *(f32x4*)&sm[b * 128 + o4 * 4] = v;
#pragma unroll
    for (int j = 0; j < 4; ++j) { s += v[j]; sq += v[j] * v[j]; }
  }
  rs[t] = s; rq[t] = sq;
  __syncthreads();
  for (int off = 128; off > 0; off >>= 1) {
    if (t < off) { rs[t] += rs[t + off]; rq[t] += rq[t + off]; }
    __syncthreads();
  }
  if (t == 0) {
    float mean = rs[0] * (1.f / 4096.f);
    float var = rq[0] * (1.f / 4096.f) - mean * mean;   // biased, torch BN1d
    float rstd = rsqrtf(var + 1e-5f);
    float sc = gg[n] * rstd;
    bc[0] = sc;
    bc[1] = bb[n] - mean * sc;
  }
  __syncthreads();
  float sc = bc[0], sh = bc[1];
#pragma unroll
  for (int i = 0; i < 4; ++i) {
    int b = bq + i * 8;
    f32x4 v = *(const f32x4*)&sm[b * 128 + o4 * 4];
    bf16x4 o;
#pragma unroll
    for (int j = 0; j < 4; ++j) {
      float x = v[j] * sc + sh;
      o[j] = (__bf16)(x > 0.f ? x : 0.f);
    }
    *(bf16x4*)(hb + ((long)b * NNODE + n) * HIDD + o4 * 4) = o;
  }
}

extern "C" void kernel_launch(void* const* d_in, const int* in_sizes, int n_in,
                              void* d_out, int out_size, void* d_ws, size_t ws_size,
                              hipStream_t stream) {
  (void)in_sizes; (void)n_in; (void)out_size; (void)ws_size;
  const float* x   = (const float*)d_in[0];
  const float* adj = (const float*)d_in[1];
  const float* wself[3] = {(const float*)d_in[2],  (const float*)d_in[8],  (const float*)d_in[14]};
  const float* bself[3] = {(const float*)d_in[3],  (const float*)d_in[9],  (const float*)d_in[15]};
  const float* wedge[3] = {(const float*)d_in[4],  (const float*)d_in[10], (const float*)d_in[16]};
  const float* bedge[3] = {(const float*)d_in[5],  (const float*)d_in[11], (const float*)d_in[17]};
  const float* bng[3]   = {(const float*)d_in[6],  (const float*)d_in[12], (const float*)d_in[18]};
  const float* bnb[3]   = {(const float*)d_in[7],  (const float*)d_in[13], (const float*)d_in[19]};
  const float* w1   = (const float*)d_in[20];
  const float* b1   = (const float*)d_in[21];
  const float* bnfg = (const float*)d_in[22];
  const float* bnfb = (const float*)d_in[23];
  const float* w2   = (const float*)d_in[24];
  const float* b2   = (const float*)d_in[25];

  char* ws = (char*)d_ws;
  __bf16*   mmp  = (__bf16*)ws;                  // 16,777,216
  float*    hs   = (float*)(ws + 16777216);      //  8,388,608
  float*    part = (float*)(ws + 25165824);      // 33,554,432 (4 x 8 MB)
  __bf16*   hb0  = (__bf16*)(ws + 58720256);     //  4,194,304
  __bf16*   hb1  = (__bf16*)(ws + 62914560);     //  4,194,304
  uint32_t* bm   = (uint32_t*)(ws + 67108864);   //  4,194,304
  float*    degp = (float*)(ws + 71303168);      //    262,144
  float*    inv  = (float*)(ws + 71565312);      //     65,536
  __bf16*   wp   = (__bf16*)(ws + 71630848);     //    475,136 -> ~72.1 MB total

  k_pack<<<16384, 256, 0, stream>>>(adj, bm, degp);
  k_inv<<<64, 256, 0, stream>>>(degp, inv);
  k_prep<<<dim3(256, 8), 256, 0, stream>>>(wself[0], wedge[0], wself[1], wedge[1],
                                           wself[2], wedge[2], w1, w2, wp);

  // layer 0 (K=64, fp32 input x converted in-staging)
  k_gemm<64, true><<<dim3(256, 10), 256, 0, stream>>>(x, wp + WP_S0, bself[0], wp + WP_E0,
                                                      bedge[0], inv, hs, mmp);
  k_spmm<<<1024, 256, 0, stream>>>(bm, mmp, part);
  k_bnstat<true><<<512, 256, 0, stream>>>(hs, part, bng[0], bnb[0], hb0);

  // layer 1 (K=128)
  k_gemm<128, false><<<dim3(256, 10), 256, 0, stream>>>(hb0, wp + WP_S1, bself[1], wp + WP_E1,
                                                        bedge[1], inv, hs, mmp);
  k_spmm<<<1024, 256, 0, stream>>>(bm, mmp, part);
  k_bnstat<true><<<512, 256, 0, stream>>>(hs, part, bng[1], bnb[1], hb1);

  // layer 2 (K=128)
  k_gemm<128, false><<<dim3(256, 10), 256, 0, stream>>>(hb1, wp + WP_S2, bself[2], wp + WP_E2,
                                                        bedge[2], inv, hs, mmp);
  k_spmm<<<1024, 256, 0, stream>>>(bm, mmp, part);
  k_bnstat<true><<<512, 256, 0, stream>>>(hs, part, bng[2], bnb[2], hb0);

  // head
  k_gemm<128, false><<<dim3(256, 2), 256, 0, stream>>>(hb0, wp + WP_W1, b1, nullptr,
                                                       nullptr, nullptr, hs, nullptr);
  k_bnstat<false><<<512, 256, 0, stream>>>(hs, nullptr, bnfg, bnfb, hb1);
  k_gemm<128, false><<<dim3(256, 2), 256, 0, stream>>>(hb1, wp + WP_W2, b2, nullptr,
                                                       nullptr, nullptr, (float*)d_out, nullptr);
}